// Round 2
// baseline (4837.586 us; speedup 1.0000x reference)
//
#include <hip/hip_runtime.h>
#include <hip/hip_bf16.h>
#include <stdint.h>

#define N_ROWS 8192
#define DM     1024     // d_model
#define DS     16384    // d_sae
#define KTOP   64
#define CAND_CAP 256

// ---------------------------------------------------------------------------
// Kernel 1: transpose W_dec [DM x DS] -> Wt [DS x DM] (for coalesced decode)
// ---------------------------------------------------------------------------
__global__ __launch_bounds__(256) void transpose_wdec(const float* __restrict__ W,
                                                      float* __restrict__ Wt) {
    __shared__ float tile[32][33];
    const int tx = threadIdx.x;        // 0..31
    const int ty = threadIdx.y;        // 0..7
    const int s0 = blockIdx.x * 32;    // along DS
    const int d0 = blockIdx.y * 32;    // along DM
#pragma unroll
    for (int j = 0; j < 32; j += 8)
        tile[ty + j][tx] = W[(size_t)(d0 + ty + j) * DS + (s0 + tx)];
    __syncthreads();
#pragma unroll
    for (int j = 0; j < 32; j += 8)
        Wt[(size_t)(s0 + ty + j) * DM + (d0 + tx)] = tile[tx][ty + j];
}

// ---------------------------------------------------------------------------
// Kernel 2: encoder GEMM  h = relu(x @ W_enc^T + b)   (fp32, vector ALU)
// 128x128 block tile, 256 threads, 8x8 micro-tile (split 4+4), TK=16
// ---------------------------------------------------------------------------
#define TM 128
#define TS 128
#define TK 16
#define LDP (TM + 4)   // padded LDS row (528B row stride: still 16B aligned)

__global__ __launch_bounds__(256) void enc_gemm(const float* __restrict__ x,
                                                const float* __restrict__ W,
                                                const float* __restrict__ b,
                                                float* __restrict__ h) {
    __shared__ float As[TK][LDP];
    __shared__ float Ws[TK][LDP];

    const int tid  = threadIdx.x;
    const int tx   = tid & 15;     // S micro dir
    const int ty   = tid >> 4;     // M micro dir
    const int row0 = blockIdx.y * TM;
    const int s0   = blockIdx.x * TS;

    const int lm = tid >> 2;          // 0..63
    const int lk = (tid & 3) * 4;     // 0,4,8,12

    float acc[8][8];
#pragma unroll
    for (int i = 0; i < 8; ++i)
#pragma unroll
        for (int j = 0; j < 8; ++j) acc[i][j] = 0.0f;

    float4 a0 = *(const float4*)&x[(size_t)(row0 + lm) * DM + lk];
    float4 a1 = *(const float4*)&x[(size_t)(row0 + lm + 64) * DM + lk];
    float4 w0 = *(const float4*)&W[(size_t)(s0 + lm) * DM + lk];
    float4 w1 = *(const float4*)&W[(size_t)(s0 + lm + 64) * DM + lk];

    for (int k0 = 0; k0 < DM; k0 += TK) {
        __syncthreads();
        As[lk + 0][lm] = a0.x; As[lk + 1][lm] = a0.y;
        As[lk + 2][lm] = a0.z; As[lk + 3][lm] = a0.w;
        As[lk + 0][lm + 64] = a1.x; As[lk + 1][lm + 64] = a1.y;
        As[lk + 2][lm + 64] = a1.z; As[lk + 3][lm + 64] = a1.w;
        Ws[lk + 0][lm] = w0.x; Ws[lk + 1][lm] = w0.y;
        Ws[lk + 2][lm] = w0.z; Ws[lk + 3][lm] = w0.w;
        Ws[lk + 0][lm + 64] = w1.x; Ws[lk + 1][lm + 64] = w1.y;
        Ws[lk + 2][lm + 64] = w1.z; Ws[lk + 3][lm + 64] = w1.w;
        __syncthreads();

        const int kn = (k0 + TK < DM) ? (k0 + TK) : k0;
        a0 = *(const float4*)&x[(size_t)(row0 + lm) * DM + kn + lk];
        a1 = *(const float4*)&x[(size_t)(row0 + lm + 64) * DM + kn + lk];
        w0 = *(const float4*)&W[(size_t)(s0 + lm) * DM + kn + lk];
        w1 = *(const float4*)&W[(size_t)(s0 + lm + 64) * DM + kn + lk];

#pragma unroll
        for (int kk = 0; kk < TK; ++kk) {
            float4 aA = *(const float4*)&As[kk][ty * 4];
            float4 aB = *(const float4*)&As[kk][ty * 4 + 64];
            float4 wA = *(const float4*)&Ws[kk][tx * 4];
            float4 wB = *(const float4*)&Ws[kk][tx * 4 + 64];
            float am[8] = {aA.x, aA.y, aA.z, aA.w, aB.x, aB.y, aB.z, aB.w};
            float wn[8] = {wA.x, wA.y, wA.z, wA.w, wB.x, wB.y, wB.z, wB.w};
#pragma unroll
            for (int i = 0; i < 8; ++i)
#pragma unroll
                for (int j = 0; j < 8; ++j)
                    acc[i][j] = fmaf(am[i], wn[j], acc[i][j]);
        }
    }

    float blo[4], bhi[4];
#pragma unroll
    for (int u = 0; u < 4; ++u) {
        blo[u] = b[s0 + tx * 4 + u];
        bhi[u] = b[s0 + 64 + tx * 4 + u];
    }
#pragma unroll
    for (int i = 0; i < 8; ++i) {
        const int r = (i < 4) ? (row0 + ty * 4 + i) : (row0 + 64 + ty * 4 + (i - 4));
        float4 lo, hi;
        lo.x = fmaxf(acc[i][0] + blo[0], 0.0f);
        lo.y = fmaxf(acc[i][1] + blo[1], 0.0f);
        lo.z = fmaxf(acc[i][2] + blo[2], 0.0f);
        lo.w = fmaxf(acc[i][3] + blo[3], 0.0f);
        hi.x = fmaxf(acc[i][4] + bhi[0], 0.0f);
        hi.y = fmaxf(acc[i][5] + bhi[1], 0.0f);
        hi.z = fmaxf(acc[i][6] + bhi[2], 0.0f);
        hi.w = fmaxf(acc[i][7] + bhi[3], 0.0f);
        *(float4*)&h[(size_t)r * DS + s0 + tx * 4]      = lo;
        *(float4*)&h[(size_t)r * DS + s0 + 64 + tx * 4] = hi;
    }
}

// ---------------------------------------------------------------------------
// Kernel 3: per-row top-64 select + prune, with fp64 resolution of the
// boundary band. fp32 radix-select gives threshold T; elements within
// +-DELTA of T are recomputed in fp64 (exact to ~1e-13) and membership is
// decided on fp64 values with lowest-index tie-break (jax top_k semantics).
// DELTA=2.5e-4 >> worst-case fp32 accumulation error (~1.5e-5), expected
// band population ~0.3 elements/row.
// ---------------------------------------------------------------------------
__global__ __launch_bounds__(256) void topk_prune(const float* __restrict__ x,
                                                  const float* __restrict__ W,
                                                  const float* __restrict__ b,
                                                  float* __restrict__ h) {
    const int row = blockIdx.x;
    float* hrow = h + (size_t)row * DS;
    const int tid = threadIdx.x;

    __shared__ unsigned hist[256];
    __shared__ unsigned sh_prefix;
    __shared__ int sh_k;

    if (tid == 0) { sh_prefix = 0u; sh_k = KTOP; }
    __syncthreads();

    // 4-pass MSB-first radix select -> exact fp32 bit pattern T of the
    // 64th-largest value (values are >=0 so uint order == float order).
    for (int pass = 0; pass < 4; ++pass) {
        const int shift = 24 - 8 * pass;
        hist[tid] = 0u;
        __syncthreads();
        const unsigned pfx = sh_prefix;
        for (int i = tid; i < DS; i += 256) {
            const unsigned u = __float_as_uint(hrow[i]);
            const bool ok = (pass == 0) || ((u >> (shift + 8)) == pfx);
            if (ok) atomicAdd(&hist[(u >> shift) & 255u], 1u);
        }
        __syncthreads();
        if (tid == 0) {
            const int k = sh_k;
            unsigned cum = 0;
            int bsel = 255;
            for (; bsel >= 0; --bsel) {
                const unsigned c = hist[bsel];
                if (cum + c >= (unsigned)k) break;
                cum += c;
            }
            sh_k = k - (int)cum;
            sh_prefix = (pfx << 8) | (unsigned)bsel;
        }
        __syncthreads();
    }
    const unsigned T = sh_prefix;
    if (T == 0u) return;  // < 64 positives: every positive is kept, zeros are zeros

    const float Tv = __uint_as_float(T);
    const float delta = (Tv > 0.01f) ? 2.5e-4f : 0.0f;  // guard tiny-threshold edge
    const float loF = Tv - delta;
    const float hiF = Tv + delta;

    __shared__ int cand_idx[CAND_CAP];
    __shared__ int cand_cnt;
    __shared__ int sure_in;
    if (tid == 0) { cand_cnt = 0; sure_in = 0; }
    __syncthreads();

    int local_sure = 0;
    for (int i = tid; i < DS; i += 256) {
        const float v = hrow[i];
        if (v > hiF) {
            ++local_sure;
        } else if (v >= loF) {
            const int p = atomicAdd(&cand_cnt, 1);
            if (p < CAND_CAP) cand_idx[p] = i;
        } else if (v != 0.0f) {
            hrow[i] = 0.0f;   // definitely out
        }
    }
    atomicAdd(&sure_in, local_sure);
    __syncthreads();

    const int nc = cand_cnt < CAND_CAP ? cand_cnt : CAND_CAP;
    const int need = KTOP - sure_in;   // >= 1 by construction
    if (nc <= need) return;            // all candidates kept

    // fp64 recompute of candidate pre-activations (cooperative dot products)
    __shared__ double cand_val[CAND_CAP];
    __shared__ double red[256];
    const float* xrow = x + (size_t)row * DM;
    for (int j = 0; j < nc; ++j) {
        const float* wrow = W + (size_t)cand_idx[j] * DM;
        const int k = tid * 4;   // 256*4 == DM
        double s = (double)xrow[k + 0] * (double)wrow[k + 0]
                 + (double)xrow[k + 1] * (double)wrow[k + 1]
                 + (double)xrow[k + 2] * (double)wrow[k + 2]
                 + (double)xrow[k + 3] * (double)wrow[k + 3];
        red[tid] = s;
        __syncthreads();
        for (int off = 128; off > 0; off >>= 1) {
            if (tid < off) red[tid] += red[tid + off];
            __syncthreads();
        }
        if (tid == 0) cand_val[j] = red[0] + (double)b[cand_idx[j]];
        __syncthreads();
    }

    // keep top-'need' candidates by (fp64 value desc, index asc); zero rest
    if (tid == 0) {
        bool keep[CAND_CAP];
        for (int j = 0; j < nc; ++j) keep[j] = false;
        for (int t = 0; t < need; ++t) {
            int best = -1;
            for (int j = 0; j < nc; ++j) {
                if (keep[j]) continue;
                if (best < 0 || cand_val[j] > cand_val[best] ||
                    (cand_val[j] == cand_val[best] && cand_idx[j] < cand_idx[best]))
                    best = j;
            }
            keep[best] = true;
        }
        for (int j = 0; j < nc; ++j)
            if (!keep[j]) hrow[cand_idx[j]] = 0.0f;
    }
}

// ---------------------------------------------------------------------------
// Kernel 4: sparse decode  recon[n,:] = sum_j h[n,s_j] * W_dec[:, s_j]
// ---------------------------------------------------------------------------
__global__ __launch_bounds__(256) void decode(const float* __restrict__ h,
                                              const float* __restrict__ Wt,
                                              const float* __restrict__ Wdec,
                                              const int use_wt,
                                              float* __restrict__ recon) {
    const int row = blockIdx.x;
    const float* hrow = h + (size_t)row * DS;
    const int tid = threadIdx.x;

    __shared__ int   s_idx[KTOP];
    __shared__ float s_val[KTOP];
    __shared__ int   s_cnt;

    if (tid == 0) s_cnt = 0;
    __syncthreads();
    for (int i = tid; i < DS; i += 256) {
        const float v = hrow[i];
        if (v != 0.0f) {
            const int p = atomicAdd(&s_cnt, 1);
            if (p < KTOP) { s_idx[p] = i; s_val[p] = v; }
        }
    }
    __syncthreads();
    const int cnt = s_cnt < KTOP ? s_cnt : KTOP;

    const int d = tid * 4;  // 256*4 == DM
    float4 acc = {0.0f, 0.0f, 0.0f, 0.0f};
    if (use_wt) {
        for (int j = 0; j < cnt; ++j) {
            const float v = s_val[j];
            const float4 w = *(const float4*)&Wt[(size_t)s_idx[j] * DM + d];
            acc.x = fmaf(v, w.x, acc.x);
            acc.y = fmaf(v, w.y, acc.y);
            acc.z = fmaf(v, w.z, acc.z);
            acc.w = fmaf(v, w.w, acc.w);
        }
    } else {
        for (int j = 0; j < cnt; ++j) {
            const float v = s_val[j];
            const int s = s_idx[j];
            acc.x = fmaf(v, Wdec[(size_t)(d + 0) * DS + s], acc.x);
            acc.y = fmaf(v, Wdec[(size_t)(d + 1) * DS + s], acc.y);
            acc.z = fmaf(v, Wdec[(size_t)(d + 2) * DS + s], acc.z);
            acc.w = fmaf(v, Wdec[(size_t)(d + 3) * DS + s], acc.w);
        }
    }
    *(float4*)&recon[(size_t)row * DM + d] = acc;
}

// ---------------------------------------------------------------------------
extern "C" void kernel_launch(void* const* d_in, const int* in_sizes, int n_in,
                              void* d_out, int out_size, void* d_ws, size_t ws_size,
                              hipStream_t stream) {
    const float* x     = (const float*)d_in[0];
    const float* W_enc = (const float*)d_in[1];
    const float* b_enc = (const float*)d_in[2];
    const float* W_dec = (const float*)d_in[3];

    float* recon = (float*)d_out;
    float* h     = recon + (size_t)N_ROWS * DM;
    float* Wt    = (float*)d_ws;

    const int use_wt = (ws_size >= (size_t)DS * DM * sizeof(float)) ? 1 : 0;

    if (use_wt) {
        transpose_wdec<<<dim3(DS / 32, DM / 32), dim3(32, 8), 0, stream>>>(W_dec, Wt);
    }
    enc_gemm<<<dim3(DS / TS, N_ROWS / TM), 256, 0, stream>>>(x, W_enc, b_enc, h);
    topk_prune<<<N_ROWS, 256, 0, stream>>>(x, W_enc, b_enc, h);
    decode<<<N_ROWS, 256, 0, stream>>>(h, Wt, W_dec, use_wt, recon);
}

// Round 3
// 2631.197 us; speedup vs baseline: 1.8385x; 1.8385x over previous
//
#include <hip/hip_runtime.h>
#include <hip/hip_bf16.h>
#include <stdint.h>

#define N_ROWS 8192
#define DM     1024     // d_model
#define DS     16384    // d_sae
#define KTOP   64
#define CAND_CAP 256

typedef __attribute__((ext_vector_type(8))) short bf16x8;
typedef __attribute__((ext_vector_type(4))) float f32x4;

#define AS1 __attribute__((address_space(1)))
#define AS3 __attribute__((address_space(3)))

// ---------------------------------------------------------------------------
// Kernel 1: transpose W_dec [DM x DS] -> Wt [DS x DM] (for coalesced decode)
// ---------------------------------------------------------------------------
__global__ __launch_bounds__(256) void transpose_wdec(const float* __restrict__ W,
                                                      float* __restrict__ Wt) {
    __shared__ float tile[32][33];
    const int tx = threadIdx.x;        // 0..31
    const int ty = threadIdx.y;        // 0..7
    const int s0 = blockIdx.x * 32;    // along DS
    const int d0 = blockIdx.y * 32;    // along DM
#pragma unroll
    for (int j = 0; j < 32; j += 8)
        tile[ty + j][tx] = W[(size_t)(d0 + ty + j) * DS + (s0 + tx)];
    __syncthreads();
#pragma unroll
    for (int j = 0; j < 32; j += 8)
        Wt[(size_t)(s0 + ty + j) * DM + (d0 + tx)] = tile[tx][ty + j];
}

// ---------------------------------------------------------------------------
// Kernel 2: split fp32 -> (bf16 hi, bf16 lo) in MFMA-staging packed layout.
// Packed chunk layout (per 128-row block rb, per 32-k slab ks): 8 chunks of
// 1KB; chunk g holds rows g*16..g*16+15, lane l=(q*16+m) stores 8 bf16 =
// row (g*16+m), k = ks*32 + q*8 .. +7, at elem offset
// (rb*32+ks)*4096 + g*512 + l*8. One global_load_lds of 1KB then lands
// fragments in LDS such that lane l's 16x16x32 A/B-fragment read is
// base + l*16 (stride-1 ds_read_b128, conflict-free).
// ---------------------------------------------------------------------------
__global__ __launch_bounds__(256) void pack_bf16(const float* __restrict__ src,
                                                 __hip_bfloat16* __restrict__ hi,
                                                 __hip_bfloat16* __restrict__ lo,
                                                 int nfrag) {
    const int t = blockIdx.x * 256 + threadIdx.x;
    if (t >= nfrag) return;
    const int l  = t & 63;
    const int g  = (t >> 6) & 7;
    const int ks = (t >> 9) & 31;
    const int rb = t >> 14;
    const int m = l & 15, q = l >> 4;
    const int row = rb * 128 + g * 16 + m;
    const int k0  = ks * 32 + q * 8;
    const float* s = src + (size_t)row * DM + k0;
#pragma unroll
    for (int j = 0; j < 8; ++j) {
        const float v = s[j];
        const __hip_bfloat16 hv = __float2bfloat16(v);
        const float r = v - __bfloat162float(hv);
        hi[(size_t)t * 8 + j] = hv;
        lo[(size_t)t * 8 + j] = __float2bfloat16(r);
    }
}

// ---------------------------------------------------------------------------
// Kernel 3: encoder GEMM via bf16x3 MFMA (Markidis split):
//   pre = x_hi*w_hi + x_hi*w_lo + x_lo*w_hi   (fp32 accum, err ~1e-5)
// 128x128 tile, 4 waves, each wave 64x64 = 4x4 tiles of 16x16x32.
// BK=32. LDS 32KB: [Ahi 8K][Alo 8K][Bhi 8K][Blo 8K], staged via
// global_load_lds width 16 (8 chunks of 1KB per wave per K-step).
// ---------------------------------------------------------------------------
#define LDS_AHI 0
#define LDS_ALO 8192
#define LDS_BHI 16384
#define LDS_BLO 24576

__global__ __launch_bounds__(256) void enc_gemm_mfma(
        const __hip_bfloat16* __restrict__ xh, const __hip_bfloat16* __restrict__ xl,
        const __hip_bfloat16* __restrict__ wh, const __hip_bfloat16* __restrict__ wl,
        const float* __restrict__ bias, float* __restrict__ h) {
    __shared__ __align__(16) char lds[32768];
    const int tid  = threadIdx.x;
    const int lane = tid & 63;
    const int w    = tid >> 6;           // wave 0..3
    const int mb   = blockIdx.y;         // 0..63   (x row-block)
    const int sb   = blockIdx.x;         // 0..127  (W row-block)

    f32x4 acc[4][4];
#pragma unroll
    for (int i = 0; i < 4; ++i)
#pragma unroll
        for (int j = 0; j < 4; ++j) acc[i][j] = (f32x4){0.f, 0.f, 0.f, 0.f};

    const int gm = (w >> 1) * 4;   // this wave's A chunk base (m quadrant)
    const int gs = (w & 1) * 4;    // this wave's B chunk base (s quadrant)

    for (int ks = 0; ks < 32; ++ks) {
        const size_t abase = ((size_t)mb * 32 + ks) * 4096;
        const size_t bbase = ((size_t)sb * 32 + ks) * 4096;
        // stage: each wave copies chunks 2w, 2w+1 of all four buffers
#pragma unroll
        for (int c = 0; c < 2; ++c) {
            const int g = w * 2 + c;
            const size_t ao = abase + g * 512 + lane * 8;
            const size_t bo = bbase + g * 512 + lane * 8;
            __builtin_amdgcn_global_load_lds((const AS1 void*)(xh + ao),
                                             (AS3 void*)(lds + LDS_AHI + g * 1024), 16, 0, 0);
            __builtin_amdgcn_global_load_lds((const AS1 void*)(xl + ao),
                                             (AS3 void*)(lds + LDS_ALO + g * 1024), 16, 0, 0);
            __builtin_amdgcn_global_load_lds((const AS1 void*)(wh + bo),
                                             (AS3 void*)(lds + LDS_BHI + g * 1024), 16, 0, 0);
            __builtin_amdgcn_global_load_lds((const AS1 void*)(wl + bo),
                                             (AS3 void*)(lds + LDS_BLO + g * 1024), 16, 0, 0);
        }
        __syncthreads();   // drains vmcnt -> LDS tiles valid

        bf16x8 ah[4], al[4], bh[4], bl[4];
#pragma unroll
        for (int t = 0; t < 4; ++t) {
            ah[t] = *((const bf16x8*)(lds + LDS_AHI + (gm + t) * 1024) + lane);
            al[t] = *((const bf16x8*)(lds + LDS_ALO + (gm + t) * 1024) + lane);
            bh[t] = *((const bf16x8*)(lds + LDS_BHI + (gs + t) * 1024) + lane);
            bl[t] = *((const bf16x8*)(lds + LDS_BLO + (gs + t) * 1024) + lane);
        }
#pragma unroll
        for (int tm = 0; tm < 4; ++tm)
#pragma unroll
            for (int ts = 0; ts < 4; ++ts) {
                acc[tm][ts] = __builtin_amdgcn_mfma_f32_16x16x32_bf16(ah[tm], bh[ts], acc[tm][ts], 0, 0, 0);
                acc[tm][ts] = __builtin_amdgcn_mfma_f32_16x16x32_bf16(ah[tm], bl[ts], acc[tm][ts], 0, 0, 0);
                acc[tm][ts] = __builtin_amdgcn_mfma_f32_16x16x32_bf16(al[tm], bh[ts], acc[tm][ts], 0, 0, 0);
            }
        __syncthreads();   // protect LDS before next stage
    }

    // epilogue: C/D layout col=lane&15 (s), row=(lane>>4)*4+reg (m)
    const int m0 = mb * 128 + (w >> 1) * 64 + (lane >> 4) * 4;
    const int s0 = sb * 128 + (w & 1) * 64 + (lane & 15);
#pragma unroll
    for (int ts = 0; ts < 4; ++ts) {
        const int s = s0 + ts * 16;
        const float bb = bias[s];
#pragma unroll
        for (int tm = 0; tm < 4; ++tm) {
            const int m = m0 + tm * 16;
#pragma unroll
            for (int r = 0; r < 4; ++r)
                h[(size_t)(m + r) * DS + s] = fmaxf(acc[tm][ts][r] + bb, 0.0f);
        }
    }
}

// ---------------------------------------------------------------------------
// Kernel 2b: fp32 fallback GEMM (proven in R2) if ws too small for packing
// ---------------------------------------------------------------------------
#define TM 128
#define TS 128
#define TK 16
#define LDP (TM + 4)

__global__ __launch_bounds__(256) void enc_gemm(const float* __restrict__ x,
                                                const float* __restrict__ W,
                                                const float* __restrict__ b,
                                                float* __restrict__ h) {
    __shared__ float As[TK][LDP];
    __shared__ float Ws[TK][LDP];
    const int tid  = threadIdx.x;
    const int tx   = tid & 15;
    const int ty   = tid >> 4;
    const int row0 = blockIdx.y * TM;
    const int s0   = blockIdx.x * TS;
    const int lm = tid >> 2;
    const int lk = (tid & 3) * 4;

    float acc[8][8];
#pragma unroll
    for (int i = 0; i < 8; ++i)
#pragma unroll
        for (int j = 0; j < 8; ++j) acc[i][j] = 0.0f;

    float4 a0 = *(const float4*)&x[(size_t)(row0 + lm) * DM + lk];
    float4 a1 = *(const float4*)&x[(size_t)(row0 + lm + 64) * DM + lk];
    float4 w0 = *(const float4*)&W[(size_t)(s0 + lm) * DM + lk];
    float4 w1 = *(const float4*)&W[(size_t)(s0 + lm + 64) * DM + lk];

    for (int k0 = 0; k0 < DM; k0 += TK) {
        __syncthreads();
        As[lk + 0][lm] = a0.x; As[lk + 1][lm] = a0.y;
        As[lk + 2][lm] = a0.z; As[lk + 3][lm] = a0.w;
        As[lk + 0][lm + 64] = a1.x; As[lk + 1][lm + 64] = a1.y;
        As[lk + 2][lm + 64] = a1.z; As[lk + 3][lm + 64] = a1.w;
        Ws[lk + 0][lm] = w0.x; Ws[lk + 1][lm] = w0.y;
        Ws[lk + 2][lm] = w0.z; Ws[lk + 3][lm] = w0.w;
        Ws[lk + 0][lm + 64] = w1.x; Ws[lk + 1][lm + 64] = w1.y;
        Ws[lk + 2][lm + 64] = w1.z; Ws[lk + 3][lm + 64] = w1.w;
        __syncthreads();
        const int kn = (k0 + TK < DM) ? (k0 + TK) : k0;
        a0 = *(const float4*)&x[(size_t)(row0 + lm) * DM + kn + lk];
        a1 = *(const float4*)&x[(size_t)(row0 + lm + 64) * DM + kn + lk];
        w0 = *(const float4*)&W[(size_t)(s0 + lm) * DM + kn + lk];
        w1 = *(const float4*)&W[(size_t)(s0 + lm + 64) * DM + kn + lk];
#pragma unroll
        for (int kk = 0; kk < TK; ++kk) {
            float4 aA = *(const float4*)&As[kk][ty * 4];
            float4 aB = *(const float4*)&As[kk][ty * 4 + 64];
            float4 wA = *(const float4*)&Ws[kk][tx * 4];
            float4 wB = *(const float4*)&Ws[kk][tx * 4 + 64];
            float am[8] = {aA.x, aA.y, aA.z, aA.w, aB.x, aB.y, aB.z, aB.w};
            float wn[8] = {wA.x, wA.y, wA.z, wA.w, wB.x, wB.y, wB.z, wB.w};
#pragma unroll
            for (int i = 0; i < 8; ++i)
#pragma unroll
                for (int j = 0; j < 8; ++j)
                    acc[i][j] = fmaf(am[i], wn[j], acc[i][j]);
        }
    }
    float blo[4], bhi[4];
#pragma unroll
    for (int u = 0; u < 4; ++u) {
        blo[u] = b[s0 + tx * 4 + u];
        bhi[u] = b[s0 + 64 + tx * 4 + u];
    }
#pragma unroll
    for (int i = 0; i < 8; ++i) {
        const int r = (i < 4) ? (row0 + ty * 4 + i) : (row0 + 64 + ty * 4 + (i - 4));
        float4 lo, hi;
        lo.x = fmaxf(acc[i][0] + blo[0], 0.0f);
        lo.y = fmaxf(acc[i][1] + blo[1], 0.0f);
        lo.z = fmaxf(acc[i][2] + blo[2], 0.0f);
        lo.w = fmaxf(acc[i][3] + blo[3], 0.0f);
        hi.x = fmaxf(acc[i][4] + bhi[0], 0.0f);
        hi.y = fmaxf(acc[i][5] + bhi[1], 0.0f);
        hi.z = fmaxf(acc[i][6] + bhi[2], 0.0f);
        hi.w = fmaxf(acc[i][7] + bhi[3], 0.0f);
        *(float4*)&h[(size_t)r * DS + s0 + tx * 4]      = lo;
        *(float4*)&h[(size_t)r * DS + s0 + 64 + tx * 4] = hi;
    }
}

// ---------------------------------------------------------------------------
// Kernel 4: per-row top-64 select + prune with fp64 boundary-band resolve
// ---------------------------------------------------------------------------
__global__ __launch_bounds__(256) void topk_prune(const float* __restrict__ x,
                                                  const float* __restrict__ W,
                                                  const float* __restrict__ b,
                                                  float* __restrict__ h) {
    const int row = blockIdx.x;
    float* hrow = h + (size_t)row * DS;
    const int tid = threadIdx.x;

    __shared__ unsigned hist[256];
    __shared__ unsigned sh_prefix;
    __shared__ int sh_k;

    if (tid == 0) { sh_prefix = 0u; sh_k = KTOP; }
    __syncthreads();

    for (int pass = 0; pass < 4; ++pass) {
        const int shift = 24 - 8 * pass;
        hist[tid] = 0u;
        __syncthreads();
        const unsigned pfx = sh_prefix;
        for (int i = tid; i < DS; i += 256) {
            const unsigned u = __float_as_uint(hrow[i]);
            const bool ok = (pass == 0) || ((u >> (shift + 8)) == pfx);
            if (ok) atomicAdd(&hist[(u >> shift) & 255u], 1u);
        }
        __syncthreads();
        if (tid == 0) {
            const int k = sh_k;
            unsigned cum = 0;
            int bsel = 255;
            for (; bsel >= 0; --bsel) {
                const unsigned c = hist[bsel];
                if (cum + c >= (unsigned)k) break;
                cum += c;
            }
            sh_k = k - (int)cum;
            sh_prefix = (pfx << 8) | (unsigned)bsel;
        }
        __syncthreads();
    }
    const unsigned T = sh_prefix;
    if (T == 0u) return;

    const float Tv = __uint_as_float(T);
    const float delta = (Tv > 0.01f) ? 2.5e-4f : 0.0f;
    const float loF = Tv - delta;
    const float hiF = Tv + delta;

    __shared__ int cand_idx[CAND_CAP];
    __shared__ int cand_cnt;
    __shared__ int sure_in;
    if (tid == 0) { cand_cnt = 0; sure_in = 0; }
    __syncthreads();

    int local_sure = 0;
    for (int i = tid; i < DS; i += 256) {
        const float v = hrow[i];
        if (v > hiF) {
            ++local_sure;
        } else if (v >= loF) {
            const int p = atomicAdd(&cand_cnt, 1);
            if (p < CAND_CAP) cand_idx[p] = i;
        } else if (v != 0.0f) {
            hrow[i] = 0.0f;
        }
    }
    atomicAdd(&sure_in, local_sure);
    __syncthreads();

    const int nc = cand_cnt < CAND_CAP ? cand_cnt : CAND_CAP;
    const int need = KTOP - sure_in;
    if (nc <= need) return;

    __shared__ double cand_val[CAND_CAP];
    __shared__ double red[256];
    const float* xrow = x + (size_t)row * DM;
    for (int j = 0; j < nc; ++j) {
        const float* wrow = W + (size_t)cand_idx[j] * DM;
        const int k = tid * 4;
        double s = (double)xrow[k + 0] * (double)wrow[k + 0]
                 + (double)xrow[k + 1] * (double)wrow[k + 1]
                 + (double)xrow[k + 2] * (double)wrow[k + 2]
                 + (double)xrow[k + 3] * (double)wrow[k + 3];
        red[tid] = s;
        __syncthreads();
        for (int off = 128; off > 0; off >>= 1) {
            if (tid < off) red[tid] += red[tid + off];
            __syncthreads();
        }
        if (tid == 0) cand_val[j] = red[0] + (double)b[cand_idx[j]];
        __syncthreads();
    }

    if (tid == 0) {
        bool keep[CAND_CAP];
        for (int j = 0; j < nc; ++j) keep[j] = false;
        for (int t = 0; t < need; ++t) {
            int best = -1;
            for (int j = 0; j < nc; ++j) {
                if (keep[j]) continue;
                if (best < 0 || cand_val[j] > cand_val[best] ||
                    (cand_val[j] == cand_val[best] && cand_idx[j] < cand_idx[best]))
                    best = j;
            }
            keep[best] = true;
        }
        for (int j = 0; j < nc; ++j)
            if (!keep[j]) hrow[cand_idx[j]] = 0.0f;
    }
}

// ---------------------------------------------------------------------------
// Kernel 5: sparse decode
// ---------------------------------------------------------------------------
__global__ __launch_bounds__(256) void decode(const float* __restrict__ h,
                                              const float* __restrict__ Wt,
                                              const float* __restrict__ Wdec,
                                              const int use_wt,
                                              float* __restrict__ recon) {
    const int row = blockIdx.x;
    const float* hrow = h + (size_t)row * DS;
    const int tid = threadIdx.x;

    __shared__ int   s_idx[KTOP];
    __shared__ float s_val[KTOP];
    __shared__ int   s_cnt;

    if (tid == 0) s_cnt = 0;
    __syncthreads();
    for (int i = tid; i < DS; i += 256) {
        const float v = hrow[i];
        if (v != 0.0f) {
            const int p = atomicAdd(&s_cnt, 1);
            if (p < KTOP) { s_idx[p] = i; s_val[p] = v; }
        }
    }
    __syncthreads();
    const int cnt = s_cnt < KTOP ? s_cnt : KTOP;

    const int d = tid * 4;
    float4 acc = {0.0f, 0.0f, 0.0f, 0.0f};
    if (use_wt) {
        for (int j = 0; j < cnt; ++j) {
            const float v = s_val[j];
            const float4 w = *(const float4*)&Wt[(size_t)s_idx[j] * DM + d];
            acc.x = fmaf(v, w.x, acc.x);
            acc.y = fmaf(v, w.y, acc.y);
            acc.z = fmaf(v, w.z, acc.z);
            acc.w = fmaf(v, w.w, acc.w);
        }
    } else {
        for (int j = 0; j < cnt; ++j) {
            const float v = s_val[j];
            const int s = s_idx[j];
            acc.x = fmaf(v, Wdec[(size_t)(d + 0) * DS + s], acc.x);
            acc.y = fmaf(v, Wdec[(size_t)(d + 1) * DS + s], acc.y);
            acc.z = fmaf(v, Wdec[(size_t)(d + 2) * DS + s], acc.z);
            acc.w = fmaf(v, Wdec[(size_t)(d + 3) * DS + s], acc.w);
        }
    }
    *(float4*)&recon[(size_t)row * DM + d] = acc;
}

// ---------------------------------------------------------------------------
extern "C" void kernel_launch(void* const* d_in, const int* in_sizes, int n_in,
                              void* d_out, int out_size, void* d_ws, size_t ws_size,
                              hipStream_t stream) {
    const float* x     = (const float*)d_in[0];
    const float* W_enc = (const float*)d_in[1];
    const float* b_enc = (const float*)d_in[2];
    const float* W_dec = (const float*)d_in[3];

    float* recon = (float*)d_out;
    float* h     = recon + (size_t)N_ROWS * DM;

    // workspace layout
    const size_t WT_BYTES = (size_t)DS * DM * sizeof(float);          // 64 MB
    const size_t XP_BYTES = (size_t)N_ROWS * DM * sizeof(__hip_bfloat16); // 16 MB
    const size_t WP_BYTES = (size_t)DS * DM * sizeof(__hip_bfloat16);     // 32 MB
    const size_t FULL_NEED = WT_BYTES + 2 * XP_BYTES + 2 * WP_BYTES;  // 160 MB

    char* wsb = (char*)d_ws;
    float* Wt = (float*)wsb;
    __hip_bfloat16* xhi = (__hip_bfloat16*)(wsb + WT_BYTES);
    __hip_bfloat16* xlo = (__hip_bfloat16*)(wsb + WT_BYTES + XP_BYTES);
    __hip_bfloat16* whi = (__hip_bfloat16*)(wsb + WT_BYTES + 2 * XP_BYTES);
    __hip_bfloat16* wlo = (__hip_bfloat16*)(wsb + WT_BYTES + 2 * XP_BYTES + WP_BYTES);

    const int use_wt   = (ws_size >= WT_BYTES) ? 1 : 0;
    const int use_mfma = (ws_size >= FULL_NEED) ? 1 : 0;

    if (use_wt) {
        transpose_wdec<<<dim3(DS / 32, DM / 32), dim3(32, 8), 0, stream>>>(W_dec, Wt);
    }
    if (use_mfma) {
        const int nfrag_x = N_ROWS * DM / 8;   // 1048576
        const int nfrag_w = DS * DM / 8;       // 2097152
        pack_bf16<<<nfrag_x / 256, 256, 0, stream>>>(x, xhi, xlo, nfrag_x);
        pack_bf16<<<nfrag_w / 256, 256, 0, stream>>>(W_enc, whi, wlo, nfrag_w);
        enc_gemm_mfma<<<dim3(DS / 128, N_ROWS / 128), 256, 0, stream>>>(
            xhi, xlo, whi, wlo, b_enc, h);
    } else {
        enc_gemm<<<dim3(DS / TS, N_ROWS / TM), 256, 0, stream>>>(x, W_enc, b_enc, h);
    }
    topk_prune<<<N_ROWS, 256, 0, stream>>>(x, W_enc, b_enc, h);
    decode<<<N_ROWS, 256, 0, stream>>>(h, Wt, W_dec, use_wt, recon);
}